// Round 11
// baseline (77.765 us; speedup 1.0000x reference)
//
#include <hip/hip_runtime.h>
#include <hip/hip_bf16.h>

#define N_NODES 10000
#define N_EDGES 320000
#define HIDDEN 16
#define MSG 64
#define EDGE_FEAT 32
#define KSTEPS 17          // K = 544 = 512 (ef x hidden) + 16 (bias) + 16 (zero pad)
#define EPB 128            // edges per block (fused kernel)

typedef __attribute__((ext_vector_type(2))) _Float16 f16x2;
typedef __attribute__((ext_vector_type(4))) _Float16 f16x4;
typedef __attribute__((ext_vector_type(8))) _Float16 f16x8;
typedef __attribute__((ext_vector_type(4))) float    f32x4;

union H8 { f16x8 v; f16x2 p[4]; f16x4 q[2]; };

// ---------------------------------------------------------------------------
// Blocks [0,KSTEPS): pack WrB as f16 B-fragments (bias folded at k=512..527).
// Blocks [KSTEPS, KSTEPS+40): zero cnt.   Blocks [KSTEPS+40, ...): zero out.
// B-frag: lane holds k = ks*32 + (lane>>4)*8 + i, n = nt*16 + (lane&15).
// ---------------------------------------------------------------------------
__global__ void zero_prep(const float* __restrict__ W, const float* __restrict__ bias,
                          ushort* __restrict__ WrB, int* __restrict__ cnt,
                          float4* __restrict__ out4, int n4) {
    if (blockIdx.x < KSTEPS) {
        const int ks   = blockIdx.x;
        const int nt   = threadIdx.x >> 6;
        const int lane = threadIdx.x & 63;
        const int g    = lane >> 4;
        const int n    = nt * 16 + (lane & 15);
        ushort* dst = WrB + (((size_t)ks * 4 + nt) * 64 + lane) * 8;
        #pragma unroll
        for (int i = 0; i < 8; ++i) {
            const int k = ks * 32 + g * 8 + i;
            float v;
            if (k < 512)      v = W[(size_t)(k >> 4) * 1024 + n * 16 + (k & 15)];
            else if (k < 528) v = bias[n * 16 + (k - 512)];
            else              v = 0.0f;
            const _Float16 hv = (_Float16)v;
            dst[i] = *reinterpret_cast<const ushort*>(&hv);
        }
    } else if (blockIdx.x < KSTEPS + 40) {
        const int idx = (blockIdx.x - KSTEPS) * 256 + threadIdx.x;
        if (idx < N_NODES) cnt[idx] = 0;
    } else {
        const int i = (blockIdx.x - KSTEPS - 40) * 256 + threadIdx.x;
        if (i < n4) out4[i] = make_float4(0.f, 0.f, 0.f, 0.f);
    }
}

// ---------------------------------------------------------------------------
// rank[e] = atomicAdd(cnt[tgt[e]], 1)
// ---------------------------------------------------------------------------
__global__ __launch_bounds__(256) void rank_kernel(const int* __restrict__ tgt,
                                                   int* __restrict__ cnt,
                                                   int* __restrict__ rank) {
    const int e = blockIdx.x * 256 + threadIdx.x;
    if (e < N_EDGES) rank[e] = atomicAdd(&cnt[tgt[e]], 1);
}

// ---------------------------------------------------------------------------
// Exclusive scan of per-node counts -> starts. Wave-shuffle, 2 barriers.
// ---------------------------------------------------------------------------
__global__ __launch_bounds__(1024) void scan_kernel(const int* __restrict__ cnt,
                                                    int* __restrict__ starts) {
    __shared__ int wsum[16];
    __shared__ int wbase[16];
    const int tid  = threadIdx.x;
    const int lane = tid & 63;
    const int wv   = tid >> 6;
    int c[10];
    int s = 0;
    #pragma unroll
    for (int j = 0; j < 10; ++j) {
        const int idx = tid * 10 + j;
        c[j] = (idx < N_NODES) ? cnt[idx] : 0;
        s += c[j];
    }
    int v = s;
    #pragma unroll
    for (int d = 1; d < 64; d <<= 1) {
        const int u = __shfl_up(v, d);
        if (lane >= d) v += u;
    }
    if (lane == 63) wsum[wv] = v;
    __syncthreads();
    if (tid < 16) {
        const int w = wsum[tid];
        int iv = w;
        #pragma unroll
        for (int d = 1; d < 16; d <<= 1) {
            const int u = __shfl_up(iv, d);
            if (tid >= d) iv += u;
        }
        wbase[tid] = iv - w;
    }
    __syncthreads();
    int running = wbase[wv] + (v - s);
    #pragma unroll
    for (int j = 0; j < 10; ++j) {
        const int idx = tid * 10 + j;
        if (idx < N_NODES) starts[idx] = running;
        running += c[j];
    }
    if (tid == 1023) starts[N_NODES] = N_EDGES;
}

// ---------------------------------------------------------------------------
// Sorted edge descriptors: edesc[starts[tgt[e]]+rank[e]] = {e, src[e], tgt[e], 0}.
// ---------------------------------------------------------------------------
__global__ __launch_bounds__(256) void build_desc(
    const int* __restrict__ tgt, const int* __restrict__ rank,
    const int* __restrict__ starts, const int* __restrict__ src,
    int4* __restrict__ edesc) {
    const int e = blockIdx.x * 256 + threadIdx.x;
    if (e < N_EDGES) {
        const int t = tgt[e];
        edesc[starts[t] + rank[e]] = make_int4(e, src[e], t, 0);
    }
}

// ---------------------------------------------------------------------------
// Fused: 128 TARGET-SORTED edges per block. n-TILE-PER-WAVE split: wave nt
// owns ONE 16-col n-tile for ALL 128 edges (8 row-tiles) -> B-panel L2
// traffic cut 4x (1 B-load/ks/wave). af built from LDS ef scalar x nb regs.
// Epilogue: f16 LDS message tile + wave-uniform run-length segmented reduce.
// ---------------------------------------------------------------------------
__global__ __launch_bounds__(256, 5) void fused_msg(
    const int4*   __restrict__ edesc,
    const float*  __restrict__ ef,
    const float*  __restrict__ hidden,
    const ushort* __restrict__ WrB,
    float*        __restrict__ out)
{
    __shared__ _Float16 ef_h[EPB][36];   // cols 0..31 ef, 32 = 1.0 (bias), 33..35 = 0
    __shared__ _Float16 nb_h[EPB][16];   // gathered hidden rows (f16)
    __shared__ int      tgt_s[EPB];
    __shared__ _Float16 msg_h[EPB][68];  // message tile (f16), padded

    const int tid = threadIdx.x;
    const int s0  = blockIdx.x * EPB;

    // ---- gather: 2 threads per sorted slot; descriptor is coalesced 16B ----
    {
        const int sl = tid >> 1;
        const int hf = tid & 1;
        const int4 d = edesc[s0 + sl];
        const int e  = d.x;
        const int sn = d.y;

        const float4* ep = (const float4*)(ef + (size_t)e * EDGE_FEAT + hf * 16);
        const float4 v0 = ep[0], v1 = ep[1], v2 = ep[2], v3 = ep[3];
        _Float16* dst = &ef_h[sl][hf * 16];
        *(f16x4*)(dst + 0)  = f16x4{(_Float16)v0.x, (_Float16)v0.y, (_Float16)v0.z, (_Float16)v0.w};
        *(f16x4*)(dst + 4)  = f16x4{(_Float16)v1.x, (_Float16)v1.y, (_Float16)v1.z, (_Float16)v1.w};
        *(f16x4*)(dst + 8)  = f16x4{(_Float16)v2.x, (_Float16)v2.y, (_Float16)v2.z, (_Float16)v2.w};
        *(f16x4*)(dst + 12) = f16x4{(_Float16)v3.x, (_Float16)v3.y, (_Float16)v3.z, (_Float16)v3.w};

        const float4* hp = (const float4*)(hidden + (size_t)sn * HIDDEN + hf * 8);
        const float4 h0 = hp[0], h1 = hp[1];
        *(f16x8*)&nb_h[sl][hf * 8] =
            f16x8{(_Float16)h0.x, (_Float16)h0.y, (_Float16)h0.z, (_Float16)h0.w,
                  (_Float16)h1.x, (_Float16)h1.y, (_Float16)h1.z, (_Float16)h1.w};

        if (hf) {
            ef_h[sl][32] = (_Float16)1.0f;
            ef_h[sl][33] = (_Float16)0.0f;
            ef_h[sl][34] = (_Float16)0.0f;
            ef_h[sl][35] = (_Float16)0.0f;
        } else {
            tgt_s[sl] = d.z;
        }
    }
    __syncthreads();

    // ---- MFMA phase: wave nt owns n-tile nt for all 8 row-tiles ----
    const int nt   = tid >> 6;             // n-tile = wave id
    const int lane = tid & 63;
    const int er   = lane & 15;            // edge row within tile / C col
    const int g    = lane >> 4;
    const int hoff = (g & 1) * 8;
    const int fg   = g >> 1;

    H8 nb[8];
    #pragma unroll
    for (int rt = 0; rt < 8; ++rt)
        nb[rt].v = *(const f16x8*)&nb_h[rt * 16 + er][hoff];

    f32x4 acc[8];
    #pragma unroll
    for (int rt = 0; rt < 8; ++rt) acc[rt] = f32x4{0.f, 0.f, 0.f, 0.f};

    const f16x8* Bp = (const f16x8*)WrB;

    #pragma unroll
    for (int ks = 0; ks < KSTEPS; ++ks) {
        const f16x8 b = Bp[(ks * 4 + nt) * 64 + lane];   // ONE B-load per ks
        #pragma unroll
        for (int rt = 0; rt < 8; ++rt) {
            const _Float16 a = ef_h[rt * 16 + er][2 * ks + fg];
            const f16x2 av = {a, a};
            H8 af;
            #pragma unroll
            for (int q = 0; q < 4; ++q) af.p[q] = av * nb[rt].p[q];   // v_pk_mul_f16
            acc[rt] = __builtin_amdgcn_mfma_f32_16x16x32_f16(af.v, b, acc[rt], 0, 0, 0);
        }
    }

    // ---- C tiles -> LDS (f16): row = edge-in-block, col = nt*16 + er ----
    #pragma unroll
    for (int rt = 0; rt < 8; ++rt) {
        #pragma unroll
        for (int r = 0; r < 4; ++r) {
            msg_h[rt * 16 + g * 4 + r][nt * 16 + er] = (_Float16)acc[rt][r];
        }
    }
    __syncthreads();

    // ---- segmented reduce: wave w owns rows w*32..w*32+31, lane owns col ----
    const int c = tid & 63;
    const int rbase = (tid >> 6) * 32;
    float run = (float)msg_h[rbase][c];
    int   cur = tgt_s[rbase];
    #pragma unroll
    for (int r = 1; r < 32; ++r) {
        const int   tg = tgt_s[rbase + r];
        const float m  = (float)msg_h[rbase + r][c];
        if (tg != cur) {
            atomicAdd(out + (size_t)cur * MSG + c, run);
            cur = tg;
            run = m;
        } else {
            run += m;
        }
    }
    atomicAdd(out + (size_t)cur * MSG + c, run);
}

// ---------------------------------------------------------------------------
// Tiny zero kernel for the fallback path.
// ---------------------------------------------------------------------------
__global__ __launch_bounds__(256) void zero_out(float* __restrict__ p, int n4) {
    const int i = blockIdx.x * 256 + threadIdx.x;
    if (i < n4) ((float4*)p)[i] = make_float4(0.f, 0.f, 0.f, 0.f);
}

// ---------------------------------------------------------------------------
// Fallback (R2 structure, f16): per-edge MFMA + fp32 atomics (small ws only).
// ---------------------------------------------------------------------------
__global__ __launch_bounds__(256, 4) void msg_mfma(
    const float* __restrict__ ef, const int* __restrict__ src,
    const int* __restrict__ tgt, const float* __restrict__ hidden,
    const ushort* __restrict__ WrB, float* __restrict__ out)
{
    __shared__ float ef_s[64][36];
    __shared__ float neigh_s[64][20];
    __shared__ int   tgt_s[64];
    const int tid = threadIdx.x;
    const int e0  = blockIdx.x * 64;
    {
        const int e = tid >> 2, h4 = (tid & 3) * 4;
        const int s = src[e0 + e];
        *(float4*)&neigh_s[e][h4] = *(const float4*)(hidden + (size_t)s * HIDDEN + h4);
    }
    {
        const int e = tid >> 2, f8 = (tid & 3) * 8;
        const float* p = ef + (size_t)(e0 + e) * EDGE_FEAT + f8;
        *(float4*)&ef_s[e][f8]     = *(const float4*)(p);
        *(float4*)&ef_s[e][f8 + 4] = *(const float4*)(p + 4);
    }
    if (tid < 64) { ef_s[tid][32] = 1.0f; ef_s[tid][33] = 0.0f; tgt_s[tid] = tgt[e0 + tid]; }
    __syncthreads();
    const int wave = tid >> 6, lane = tid & 63;
    const int er = lane & 15, g = lane >> 4;
    const int e_loc = wave * 16 + er;
    const int h0 = (g & 1) * 8, fg = g >> 1;
    float nb[8];
    #pragma unroll
    for (int j = 0; j < 8; ++j) nb[j] = neigh_s[e_loc][h0 + j];
    f32x4 acc0 = {0.f,0.f,0.f,0.f}, acc1 = acc0, acc2 = acc0, acc3 = acc0;
    const f16x8* Bp = (const f16x8*)WrB;
    #pragma unroll
    for (int ks = 0; ks < KSTEPS; ++ks) {
        const float a = ef_s[e_loc][2 * ks + fg];
        f16x8 af;
        #pragma unroll
        for (int j = 0; j < 8; ++j) af[j] = (_Float16)(a * nb[j]);
        const f16x8 b0 = Bp[(ks * 4 + 0) * 64 + lane];
        const f16x8 b1 = Bp[(ks * 4 + 1) * 64 + lane];
        const f16x8 b2 = Bp[(ks * 4 + 2) * 64 + lane];
        const f16x8 b3 = Bp[(ks * 4 + 3) * 64 + lane];
        acc0 = __builtin_amdgcn_mfma_f32_16x16x32_f16(af, b0, acc0, 0, 0, 0);
        acc1 = __builtin_amdgcn_mfma_f32_16x16x32_f16(af, b1, acc1, 0, 0, 0);
        acc2 = __builtin_amdgcn_mfma_f32_16x16x32_f16(af, b2, acc2, 0, 0, 0);
        acc3 = __builtin_amdgcn_mfma_f32_16x16x32_f16(af, b3, acc3, 0, 0, 0);
    }
    #pragma unroll
    for (int r = 0; r < 4; ++r) {
        const int t = tgt_s[wave * 16 + g * 4 + r];
        float* op = out + (size_t)t * MSG;
        atomicAdd(op +      er, acc0[r]);
        atomicAdd(op + 16 + er, acc1[r]);
        atomicAdd(op + 32 + er, acc2[r]);
        atomicAdd(op + 48 + er, acc3[r]);
    }
}

extern "C" void kernel_launch(void* const* d_in, const int* in_sizes, int n_in,
                              void* d_out, int out_size, void* d_ws, size_t ws_size,
                              hipStream_t stream) {
    // inputs: 0 node_features (unused), 1 edge_features, 2 edge_sources,
    //         3 edge_targets, 4 hidden, 5 initial (unused), 6 W, 7 b
    const float* ef     = (const float*)d_in[1];
    const int*   src    = (const int*)d_in[2];
    const int*   tgt    = (const int*)d_in[3];
    const float* hidden = (const float*)d_in[4];
    const float* W      = (const float*)d_in[6];
    const float* bias   = (const float*)d_in[7];
    float* out = (float*)d_out;
    char*  ws  = (char*)d_ws;

    // ws layout (16B aligned) — ~6.6 MB
    const size_t o_wrb    = 0;            //     69,632 B
    const size_t o_starts = 69632;        //     40,004 B
    const size_t o_cnt    = 109648;       //     40,000 B
    const size_t o_rank   = 149648;       //  1,280,000 B
    const size_t o_desc   = 1429648;      //  5,120,000 B (int4 per edge)
    const size_t need     = o_desc + (size_t)N_EDGES * 16;

    ushort* WrB = (ushort*)(ws + o_wrb);
    const int n4 = out_size / 4;

    if (ws_size >= need) {
        int*  starts = (int*)(ws + o_starts);
        int*  cnt    = (int*)(ws + o_cnt);
        int*  rank   = (int*)(ws + o_rank);
        int4* edesc  = (int4*)(ws + o_desc);

        const int zb_cnt = 40;
        const int zb_out = (n4 + 255) / 256;
        zero_prep<<<KSTEPS + zb_cnt + zb_out, 256, 0, stream>>>(W, bias, WrB, cnt,
                                                                (float4*)out, n4);
        rank_kernel<<<(N_EDGES + 255) / 256, 256, 0, stream>>>(tgt, cnt, rank);
        scan_kernel<<<1, 1024, 0, stream>>>(cnt, starts);
        build_desc<<<(N_EDGES + 255) / 256, 256, 0, stream>>>(tgt, rank, starts, src, edesc);
        fused_msg<<<N_EDGES / EPB, 256, 0, stream>>>(edesc, ef, hidden, WrB, out);
    } else {
        zero_prep<<<KSTEPS, 256, 0, stream>>>(W, bias, WrB, nullptr, nullptr, 0);
        zero_out<<<(n4 + 255) / 256, 256, 0, stream>>>(out, n4);
        msg_mfma<<<N_EDGES / 64, 256, 0, stream>>>(ef, src, tgt, hidden, WrB, out);
    }
}

// Round 12
// 75.524 us; speedup vs baseline: 1.0297x; 1.0297x over previous
//
#include <hip/hip_runtime.h>
#include <hip/hip_bf16.h>

#define N_NODES 10000
#define N_EDGES 320000
#define HIDDEN 16
#define MSG 64
#define EDGE_FEAT 32
#define KSTEPS 17          // K = 544 = 512 (ef x hidden) + 16 (bias) + 16 (zero pad)
#define EPB 64             // edges per block (fused kernel) - halved for occupancy

typedef __attribute__((ext_vector_type(2))) _Float16 f16x2;
typedef __attribute__((ext_vector_type(4))) _Float16 f16x4;
typedef __attribute__((ext_vector_type(8))) _Float16 f16x8;
typedef __attribute__((ext_vector_type(4))) float    f32x4;

union H8 { f16x8 v; f16x2 p[4]; f16x4 q[2]; };

// ---------------------------------------------------------------------------
// Blocks [0,KSTEPS): pack WrB as f16 B-fragments (bias folded at k=512..527).
// Blocks [KSTEPS, KSTEPS+40): zero cnt.   Blocks [KSTEPS+40, ...): zero out.
// B-frag: lane holds k = ks*32 + (lane>>4)*8 + i, n = nt*16 + (lane&15).
// ---------------------------------------------------------------------------
__global__ void zero_prep(const float* __restrict__ W, const float* __restrict__ bias,
                          ushort* __restrict__ WrB, int* __restrict__ cnt,
                          float4* __restrict__ out4, int n4) {
    if (blockIdx.x < KSTEPS) {
        const int ks   = blockIdx.x;
        const int nt   = threadIdx.x >> 6;
        const int lane = threadIdx.x & 63;
        const int g    = lane >> 4;
        const int n    = nt * 16 + (lane & 15);
        ushort* dst = WrB + (((size_t)ks * 4 + nt) * 64 + lane) * 8;
        #pragma unroll
        for (int i = 0; i < 8; ++i) {
            const int k = ks * 32 + g * 8 + i;
            float v;
            if (k < 512)      v = W[(size_t)(k >> 4) * 1024 + n * 16 + (k & 15)];
            else if (k < 528) v = bias[n * 16 + (k - 512)];
            else              v = 0.0f;
            const _Float16 hv = (_Float16)v;
            dst[i] = *reinterpret_cast<const ushort*>(&hv);
        }
    } else if (blockIdx.x < KSTEPS + 40) {
        const int idx = (blockIdx.x - KSTEPS) * 256 + threadIdx.x;
        if (idx < N_NODES) cnt[idx] = 0;
    } else {
        const int i = (blockIdx.x - KSTEPS - 40) * 256 + threadIdx.x;
        if (i < n4) out4[i] = make_float4(0.f, 0.f, 0.f, 0.f);
    }
}

// ---------------------------------------------------------------------------
// rank[e] = atomicAdd(cnt[tgt[e]], 1)
// ---------------------------------------------------------------------------
__global__ __launch_bounds__(256) void rank_kernel(const int* __restrict__ tgt,
                                                   int* __restrict__ cnt,
                                                   int* __restrict__ rank) {
    const int e = blockIdx.x * 256 + threadIdx.x;
    if (e < N_EDGES) rank[e] = atomicAdd(&cnt[tgt[e]], 1);
}

// ---------------------------------------------------------------------------
// Exclusive scan of per-node counts -> starts. Wave-shuffle, 2 barriers.
// ---------------------------------------------------------------------------
__global__ __launch_bounds__(1024) void scan_kernel(const int* __restrict__ cnt,
                                                    int* __restrict__ starts) {
    __shared__ int wsum[16];
    __shared__ int wbase[16];
    const int tid  = threadIdx.x;
    const int lane = tid & 63;
    const int wv   = tid >> 6;
    int c[10];
    int s = 0;
    #pragma unroll
    for (int j = 0; j < 10; ++j) {
        const int idx = tid * 10 + j;
        c[j] = (idx < N_NODES) ? cnt[idx] : 0;
        s += c[j];
    }
    int v = s;
    #pragma unroll
    for (int d = 1; d < 64; d <<= 1) {
        const int u = __shfl_up(v, d);
        if (lane >= d) v += u;
    }
    if (lane == 63) wsum[wv] = v;
    __syncthreads();
    if (tid < 16) {
        const int w = wsum[tid];
        int iv = w;
        #pragma unroll
        for (int d = 1; d < 16; d <<= 1) {
            const int u = __shfl_up(iv, d);
            if (tid >= d) iv += u;
        }
        wbase[tid] = iv - w;
    }
    __syncthreads();
    int running = wbase[wv] + (v - s);
    #pragma unroll
    for (int j = 0; j < 10; ++j) {
        const int idx = tid * 10 + j;
        if (idx < N_NODES) starts[idx] = running;
        running += c[j];
    }
    if (tid == 1023) starts[N_NODES] = N_EDGES;
}

// ---------------------------------------------------------------------------
// Sorted edge descriptors: edesc[starts[tgt[e]]+rank[e]] = {e, src[e], tgt[e], 0}.
// ---------------------------------------------------------------------------
__global__ __launch_bounds__(256) void build_desc(
    const int* __restrict__ tgt, const int* __restrict__ rank,
    const int* __restrict__ starts, const int* __restrict__ src,
    int4* __restrict__ edesc) {
    const int e = blockIdx.x * 256 + threadIdx.x;
    if (e < N_EDGES) {
        const int t = tgt[e];
        edesc[starts[t] + rank[e]] = make_int4(e, src[e], t, 0);
    }
}

// ---------------------------------------------------------------------------
// Fused: 64 TARGET-SORTED edges per block, 4 waves; wave nt owns ONE 16-col
// n-tile for all 64 edges (4 row-tiles). LDS ~15.6KB -> 8 blocks/CU (100%
// occupancy cap) so 8 independent gather->MFMA->reduce pipelines overlap.
// Epilogue: f16 LDS message tile + wave-uniform run-length segmented reduce.
// ---------------------------------------------------------------------------
__global__ __launch_bounds__(256, 8) void fused_msg(
    const int4*   __restrict__ edesc,
    const float*  __restrict__ ef,
    const float*  __restrict__ hidden,
    const ushort* __restrict__ WrB,
    float*        __restrict__ out)
{
    __shared__ _Float16 ef_h[EPB][36];   // cols 0..31 ef, 32 = 1.0 (bias), 33..35 = 0
    __shared__ _Float16 nb_h[EPB][16];   // gathered hidden rows (f16)
    __shared__ int      tgt_s[EPB];
    __shared__ _Float16 msg_h[EPB][68];  // message tile (f16), padded

    const int tid = threadIdx.x;
    const int s0  = blockIdx.x * EPB;

    // ---- gather: 4 threads per sorted slot (quad shares the 16B desc) ----
    {
        const int sl = tid >> 2;
        const int q  = tid & 3;
        const int4 d = edesc[s0 + sl];
        const int e  = d.x;
        const int sn = d.y;

        const float4* ep = (const float4*)(ef + (size_t)e * EDGE_FEAT + q * 8);
        const float4 v0 = ep[0], v1 = ep[1];
        _Float16* dst = &ef_h[sl][q * 8];
        *(f16x4*)(dst + 0) = f16x4{(_Float16)v0.x, (_Float16)v0.y, (_Float16)v0.z, (_Float16)v0.w};
        *(f16x4*)(dst + 4) = f16x4{(_Float16)v1.x, (_Float16)v1.y, (_Float16)v1.z, (_Float16)v1.w};

        const float4 h0 = *(const float4*)(hidden + (size_t)sn * HIDDEN + q * 4);
        *(f16x4*)&nb_h[sl][q * 4] =
            f16x4{(_Float16)h0.x, (_Float16)h0.y, (_Float16)h0.z, (_Float16)h0.w};

        if (q == 3) {
            ef_h[sl][32] = (_Float16)1.0f;
            ef_h[sl][33] = (_Float16)0.0f;
            ef_h[sl][34] = (_Float16)0.0f;
            ef_h[sl][35] = (_Float16)0.0f;
        } else if (q == 0) {
            tgt_s[sl] = d.z;
        }
    }
    __syncthreads();

    // ---- MFMA phase: wave nt owns n-tile nt for all 4 row-tiles ----
    const int nt   = tid >> 6;             // n-tile = wave id
    const int lane = tid & 63;
    const int er   = lane & 15;            // edge row within tile / C col
    const int g    = lane >> 4;
    const int hoff = (g & 1) * 8;
    const int fg   = g >> 1;

    H8 nb[4];
    #pragma unroll
    for (int rt = 0; rt < 4; ++rt)
        nb[rt].v = *(const f16x8*)&nb_h[rt * 16 + er][hoff];

    f32x4 acc[4];
    #pragma unroll
    for (int rt = 0; rt < 4; ++rt) acc[rt] = f32x4{0.f, 0.f, 0.f, 0.f};

    const f16x8* Bp = (const f16x8*)WrB;

    #pragma unroll
    for (int ks = 0; ks < KSTEPS; ++ks) {
        const f16x8 b = Bp[(ks * 4 + nt) * 64 + lane];   // ONE B-load per ks
        #pragma unroll
        for (int rt = 0; rt < 4; ++rt) {
            const _Float16 a = ef_h[rt * 16 + er][2 * ks + fg];
            const f16x2 av = {a, a};
            H8 af;
            #pragma unroll
            for (int q = 0; q < 4; ++q) af.p[q] = av * nb[rt].p[q];   // v_pk_mul_f16
            acc[rt] = __builtin_amdgcn_mfma_f32_16x16x32_f16(af.v, b, acc[rt], 0, 0, 0);
        }
    }

    // ---- C tiles -> LDS (f16): row = edge-in-block, col = nt*16 + er ----
    #pragma unroll
    for (int rt = 0; rt < 4; ++rt) {
        #pragma unroll
        for (int r = 0; r < 4; ++r) {
            msg_h[rt * 16 + g * 4 + r][nt * 16 + er] = (_Float16)acc[rt][r];
        }
    }
    __syncthreads();

    // ---- segmented reduce: wave w owns rows w*16..w*16+15, lane owns col ----
    const int c = tid & 63;
    const int rbase = (tid >> 6) * 16;
    float run = (float)msg_h[rbase][c];
    int   cur = tgt_s[rbase];
    #pragma unroll
    for (int r = 1; r < 16; ++r) {
        const int   tg = tgt_s[rbase + r];
        const float m  = (float)msg_h[rbase + r][c];
        if (tg != cur) {
            atomicAdd(out + (size_t)cur * MSG + c, run);
            cur = tg;
            run = m;
        } else {
            run += m;
        }
    }
    atomicAdd(out + (size_t)cur * MSG + c, run);
}

// ---------------------------------------------------------------------------
// Tiny zero kernel for the fallback path.
// ---------------------------------------------------------------------------
__global__ __launch_bounds__(256) void zero_out(float* __restrict__ p, int n4) {
    const int i = blockIdx.x * 256 + threadIdx.x;
    if (i < n4) ((float4*)p)[i] = make_float4(0.f, 0.f, 0.f, 0.f);
}

// ---------------------------------------------------------------------------
// Fallback (R2 structure, f16): per-edge MFMA + fp32 atomics (small ws only).
// ---------------------------------------------------------------------------
__global__ __launch_bounds__(256, 4) void msg_mfma(
    const float* __restrict__ ef, const int* __restrict__ src,
    const int* __restrict__ tgt, const float* __restrict__ hidden,
    const ushort* __restrict__ WrB, float* __restrict__ out)
{
    __shared__ float ef_s[64][36];
    __shared__ float neigh_s[64][20];
    __shared__ int   tgt_s[64];
    const int tid = threadIdx.x;
    const int e0  = blockIdx.x * 64;
    {
        const int e = tid >> 2, h4 = (tid & 3) * 4;
        const int s = src[e0 + e];
        *(float4*)&neigh_s[e][h4] = *(const float4*)(hidden + (size_t)s * HIDDEN + h4);
    }
    {
        const int e = tid >> 2, f8 = (tid & 3) * 8;
        const float* p = ef + (size_t)(e0 + e) * EDGE_FEAT + f8;
        *(float4*)&ef_s[e][f8]     = *(const float4*)(p);
        *(float4*)&ef_s[e][f8 + 4] = *(const float4*)(p + 4);
    }
    if (tid < 64) { ef_s[tid][32] = 1.0f; ef_s[tid][33] = 0.0f; tgt_s[tid] = tgt[e0 + tid]; }
    __syncthreads();
    const int wave = tid >> 6, lane = tid & 63;
    const int er = lane & 15, g = lane >> 4;
    const int e_loc = wave * 16 + er;
    const int h0 = (g & 1) * 8, fg = g >> 1;
    float nb[8];
    #pragma unroll
    for (int j = 0; j < 8; ++j) nb[j] = neigh_s[e_loc][h0 + j];
    f32x4 acc0 = {0.f,0.f,0.f,0.f}, acc1 = acc0, acc2 = acc0, acc3 = acc0;
    const f16x8* Bp = (const f16x8*)WrB;
    #pragma unroll
    for (int ks = 0; ks < KSTEPS; ++ks) {
        const float a = ef_s[e_loc][2 * ks + fg];
        f16x8 af;
        #pragma unroll
        for (int j = 0; j < 8; ++j) af[j] = (_Float16)(a * nb[j]);
        const f16x8 b0 = Bp[(ks * 4 + 0) * 64 + lane];
        const f16x8 b1 = Bp[(ks * 4 + 1) * 64 + lane];
        const f16x8 b2 = Bp[(ks * 4 + 2) * 64 + lane];
        const f16x8 b3 = Bp[(ks * 4 + 3) * 64 + lane];
        acc0 = __builtin_amdgcn_mfma_f32_16x16x32_f16(af, b0, acc0, 0, 0, 0);
        acc1 = __builtin_amdgcn_mfma_f32_16x16x32_f16(af, b1, acc1, 0, 0, 0);
        acc2 = __builtin_amdgcn_mfma_f32_16x16x32_f16(af, b2, acc2, 0, 0, 0);
        acc3 = __builtin_amdgcn_mfma_f32_16x16x32_f16(af, b3, acc3, 0, 0, 0);
    }
    #pragma unroll
    for (int r = 0; r < 4; ++r) {
        const int t = tgt_s[wave * 16 + g * 4 + r];
        float* op = out + (size_t)t * MSG;
        atomicAdd(op +      er, acc0[r]);
        atomicAdd(op + 16 + er, acc1[r]);
        atomicAdd(op + 32 + er, acc2[r]);
        atomicAdd(op + 48 + er, acc3[r]);
    }
}

extern "C" void kernel_launch(void* const* d_in, const int* in_sizes, int n_in,
                              void* d_out, int out_size, void* d_ws, size_t ws_size,
                              hipStream_t stream) {
    // inputs: 0 node_features (unused), 1 edge_features, 2 edge_sources,
    //         3 edge_targets, 4 hidden, 5 initial (unused), 6 W, 7 b
    const float* ef     = (const float*)d_in[1];
    const int*   src    = (const int*)d_in[2];
    const int*   tgt    = (const int*)d_in[3];
    const float* hidden = (const float*)d_in[4];
    const float* W      = (const float*)d_in[6];
    const float* bias   = (const float*)d_in[7];
    float* out = (float*)d_out;
    char*  ws  = (char*)d_ws;

    // ws layout (16B aligned) — ~6.6 MB
    const size_t o_wrb    = 0;            //     69,632 B
    const size_t o_starts = 69632;        //     40,004 B
    const size_t o_cnt    = 109648;       //     40,000 B
    const size_t o_rank   = 149648;       //  1,280,000 B
    const size_t o_desc   = 1429648;      //  5,120,000 B (int4 per edge)
    const size_t need     = o_desc + (size_t)N_EDGES * 16;

    ushort* WrB = (ushort*)(ws + o_wrb);
    const int n4 = out_size / 4;

    if (ws_size >= need) {
        int*  starts = (int*)(ws + o_starts);
        int*  cnt    = (int*)(ws + o_cnt);
        int*  rank   = (int*)(ws + o_rank);
        int4* edesc  = (int4*)(ws + o_desc);

        const int zb_cnt = 40;
        const int zb_out = (n4 + 255) / 256;
        zero_prep<<<KSTEPS + zb_cnt + zb_out, 256, 0, stream>>>(W, bias, WrB, cnt,
                                                                (float4*)out, n4);
        rank_kernel<<<(N_EDGES + 255) / 256, 256, 0, stream>>>(tgt, cnt, rank);
        scan_kernel<<<1, 1024, 0, stream>>>(cnt, starts);
        build_desc<<<(N_EDGES + 255) / 256, 256, 0, stream>>>(tgt, rank, starts, src, edesc);
        fused_msg<<<N_EDGES / EPB, 256, 0, stream>>>(edesc, ef, hidden, WrB, out);
    } else {
        zero_prep<<<KSTEPS, 256, 0, stream>>>(W, bias, WrB, nullptr, nullptr, 0);
        zero_out<<<(n4 + 255) / 256, 256, 0, stream>>>(out, n4);
        msg_mfma<<<N_EDGES / 64, 256, 0, stream>>>(ef, src, tgt, hidden, WrB, out);
    }
}